// Round 4
// baseline (2060.749 us; speedup 1.0000x reference)
//
#include <hip/hip_runtime.h>
#include <math.h>

#define EXPERTS 8
#define DEPTH 6
#define DIM 512
#define HEADS 8
#define NCLS 10
#define BATCH 128
#define PD 48
#define NTOK 65

typedef __attribute__((ext_vector_type(4))) float f32x4;
typedef __attribute__((ext_vector_type(8))) __bf16 bf16x8;
typedef unsigned short u16;

__device__ inline u16 f2bf(float f) {
    union { float f; unsigned u; } v; v.f = f;
    unsigned r = v.u + 0x7FFFu + ((v.u >> 16) & 1u);
    return (u16)(r >> 16);
}
__device__ inline float bf2f(u16 s) {
    union { unsigned u; float f; } v; v.u = ((unsigned)s) << 16;
    return v.f;
}

// ---------------------------------------------------------------------------
// Gate (exact fp32 — routing must not flip)
// ---------------------------------------------------------------------------
__global__ __launch_bounds__(256) void gate_k(const float* __restrict__ x,
                                              const float* __restrict__ gw,
                                              const float* __restrict__ gb,
                                              int* __restrict__ top1) {
    int b = blockIdx.x, tid = threadIdx.x;
    const float* xb = x + (size_t)b * 3072;
    float acc[EXPERTS];
#pragma unroll
    for (int e = 0; e < EXPERTS; ++e) acc[e] = 0.f;
    for (int i = tid; i < 3072; i += 256) {
        float xv = xb[i];
#pragma unroll
        for (int e = 0; e < EXPERTS; ++e)
            acc[e] = fmaf(xv, gw[(size_t)e * 3072 + i], acc[e]);
    }
    __shared__ float red[256];
    __shared__ float logits[EXPERTS];
    for (int e = 0; e < EXPERTS; ++e) {
        red[tid] = acc[e];
        __syncthreads();
        for (int s = 128; s > 0; s >>= 1) {
            if (tid < s) red[tid] += red[tid + s];
            __syncthreads();
        }
        if (tid == 0) logits[e] = red[0] + gb[e];
        __syncthreads();
    }
    if (tid == 0) {
        int best = 0;
        float bv = logits[0];
        for (int e = 1; e < EXPERTS; ++e)
            if (logits[e] > bv) { bv = logits[e]; best = e; }
        top1[b] = best;
    }
}

// ---------------------------------------------------------------------------
// Routing tables: per-expert item lists, padded to G=2 (68 groups) and
// G=4 (38 groups). Dummy slots = -1, empty groups gexp = -1.
// ---------------------------------------------------------------------------
__global__ __launch_bounds__(256) void route_k(const int* __restrict__ top1,
                                               int* __restrict__ perm2,
                                               int* __restrict__ gexp2,
                                               int* __restrict__ perm4,
                                               int* __restrict__ gexp4) {
    __shared__ int t1[BATCH];
    int tid = threadIdx.x;
    if (tid < BATCH) t1[tid] = top1[tid];
    __syncthreads();
    if (tid != 0) return;
    int p2 = 0, p4 = 0;
    for (int e = 0; e < EXPERTS; ++e) {
        int s2 = p2, s4 = p4;
        for (int b = 0; b < BATCH; ++b)
            if (t1[b] == e) { perm2[p2++] = b; perm4[p4++] = b; }
        if (p2 == s2) continue;
        while (p2 & 1) perm2[p2++] = -1;
        while (p4 & 3) perm4[p4++] = -1;
        for (int g = s2 >> 1; g < (p2 >> 1); ++g) gexp2[g] = e;
        for (int g = s4 >> 2; g < (p4 >> 2); ++g) gexp4[g] = e;
    }
    for (int i = p2; i < 136; ++i) perm2[i] = -1;
    for (int i = p4; i < 152; ++i) perm4[i] = -1;
    for (int g = p2 >> 1; g < 68; ++g) gexp2[g] = -1;
    for (int g = p4 >> 2; g < 38; ++g) gexp4[g] = -1;
}

// ---------------------------------------------------------------------------
// Patch embed (fp32, writes residual stream t)
// ---------------------------------------------------------------------------
__global__ __launch_bounds__(256) void patch_k(const float* __restrict__ x,
                                               const float* __restrict__ pln1_g,
                                               const float* __restrict__ pln1_b,
                                               const float* __restrict__ patch_w,
                                               const float* __restrict__ patch_b,
                                               const float* __restrict__ pln2_g,
                                               const float* __restrict__ pln2_b,
                                               const float* __restrict__ cls_tok,
                                               const float* __restrict__ pos_emb,
                                               const int* __restrict__ top1,
                                               float* __restrict__ t) {
    int n = blockIdx.x, b = blockIdx.y, tid = threadIdx.x;
    int e = top1[b];
    float* trow = t + ((size_t)b * NTOK + n) * DIM;
    const float* pe = pos_emb + ((size_t)e * NTOK + n) * DIM;

    if (n == 0) {
        for (int d = tid; d < DIM; d += 256)
            trow[d] = cls_tok[e * DIM + d] + pe[d];
        return;
    }
    int pi = n - 1, h = pi >> 3, w = pi & 7;
    __shared__ float pv[PD];
    __shared__ float red[256];
    if (tid < PD) {
        int p1 = tid / 12, rem = tid % 12, p2 = rem / 3, c = rem % 3;
        pv[tid] = x[((size_t)b * 3 + c) * 1024 + (h * 4 + p1) * 32 + (w * 4 + p2)];
    }
    __syncthreads();
    float m = 0.f, q = 0.f;
    for (int j = 0; j < PD; ++j) { float v = pv[j]; m += v; q += v * v; }
    m *= (1.f / PD);
    q = q * (1.f / PD) - m * m;
    float rs = rsqrtf(q + 1e-5f);
    __syncthreads();
    if (tid < PD)
        pv[tid] = (pv[tid] - m) * rs * pln1_g[e * PD + tid] + pln1_b[e * PD + tid];
    __syncthreads();

    float acc0 = patch_b[e * DIM + tid];
    float acc1 = patch_b[e * DIM + tid + 256];
    for (int j = 0; j < PD; ++j) {
        float v = pv[j];
        const float* wr = patch_w + ((size_t)e * PD + j) * DIM;
        acc0 = fmaf(v, wr[tid], acc0);
        acc1 = fmaf(v, wr[tid + 256], acc1);
    }
    red[tid] = acc0 + acc1;
    __syncthreads();
    for (int s = 128; s > 0; s >>= 1) {
        if (tid < s) red[tid] += red[tid + s];
        __syncthreads();
    }
    float S = red[0];
    __syncthreads();
    red[tid] = acc0 * acc0 + acc1 * acc1;
    __syncthreads();
    for (int s = 128; s > 0; s >>= 1) {
        if (tid < s) red[tid] += red[tid + s];
        __syncthreads();
    }
    float Q = red[0];
    float mean = S * (1.f / DIM);
    float var = Q * (1.f / DIM) - mean * mean;
    float rs2 = rsqrtf(var + 1e-5f);
    trow[tid]       = (acc0 - mean) * rs2 * pln2_g[e * DIM + tid]       + pln2_b[e * DIM + tid]       + pe[tid];
    trow[tid + 256] = (acc1 - mean) * rs2 * pln2_g[e * DIM + tid + 256] + pln2_b[e * DIM + tid + 256] + pe[tid + 256];
}

// ---------------------------------------------------------------------------
// LayerNorm: fp32 src -> bf16 dst
// ---------------------------------------------------------------------------
__global__ __launch_bounds__(256) void ln_k(const float* __restrict__ src,
                                            u16* __restrict__ dst,
                                            const float* __restrict__ gbase,
                                            const float* __restrict__ bbase,
                                            const int* __restrict__ top1,
                                            int estride) {
    int n = blockIdx.x, b = blockIdx.y, tid = threadIdx.x;
    int e = top1[b];
    size_t row = ((size_t)b * NTOK + n) * DIM;
    const float* gamma = gbase + (size_t)e * estride;
    const float* beta  = bbase + (size_t)e * estride;
    float v0 = src[row + tid], v1 = src[row + tid + 256];
    __shared__ float red[256];
    red[tid] = v0 + v1;
    __syncthreads();
    for (int s = 128; s > 0; s >>= 1) {
        if (tid < s) red[tid] += red[tid + s];
        __syncthreads();
    }
    float S = red[0];
    __syncthreads();
    red[tid] = v0 * v0 + v1 * v1;
    __syncthreads();
    for (int s = 128; s > 0; s >>= 1) {
        if (tid < s) red[tid] += red[tid + s];
        __syncthreads();
    }
    float Q = red[0];
    float mean = S * (1.f / DIM);
    float var = Q * (1.f / DIM) - mean * mean;
    float rs = rsqrtf(var + 1e-5f);
    dst[row + tid]       = f2bf((v0 - mean) * rs * gamma[tid]       + beta[tid]);
    dst[row + tid + 256] = f2bf((v1 - mean) * rs * gamma[tid + 256] + beta[tid + 256]);
}

// ---------------------------------------------------------------------------
// Weight convert: fp32 [cnt][512][N] -> bf16 [cnt][N][512] (transpose).
// ---------------------------------------------------------------------------
__global__ __launch_bounds__(256) void wconv_k(const float* __restrict__ src,
                                               u16* __restrict__ dst, int N) {
    __shared__ float tile[32][33];
    int n0 = blockIdx.x * 32, k0 = blockIdx.y * 32, m = blockIdx.z;
    const float* s = src + (size_t)m * 512 * N;
    u16* d = dst + (size_t)m * 512 * N;
    int r = threadIdx.x >> 5, c = threadIdx.x & 31;
#pragma unroll
    for (int i = 0; i < 4; ++i)
        tile[r + i * 8][c] = s[(size_t)(k0 + r + i * 8) * N + n0 + c];
    __syncthreads();
#pragma unroll
    for (int i = 0; i < 4; ++i)
        d[(size_t)(n0 + r + i * 8) * 512 + k0 + c] = f2bf(tile[c][r + i * 8]);
}

// ---------------------------------------------------------------------------
// Expert-grouped MFMA GEMM: G items per block share one expert's weights.
// C[g.items, 65, N-tile] = A @ Wt (bf16, Wt[n][k]). grid (N/128, NGROUPS).
// OP: 0 = store bf16; 1 = fp32 residual += acc+bias; 2 = bias+GELU -> bf16
// ---------------------------------------------------------------------------
template <int N, int OP, int G>
__global__ __launch_bounds__(256) void mgemm3_k(const u16* __restrict__ A,
                                                const u16* __restrict__ Wtbase,
                                                const float* __restrict__ Bbase,
                                                void* __restrict__ Cptr,
                                                const int* __restrict__ perm,
                                                const int* __restrict__ gexp,
                                                int westride, int bestride) {
    constexpr int MR = 65 * G;
    constexpr int MT = (MR + 15) / 16;
    constexpr int ROWS = MT * 16;

    int gid = blockIdx.y;
    int e = gexp[gid];
    if (e < 0) return;
    int ct = blockIdx.x, tid = threadIdx.x;
    const u16* Wt = Wtbase + (size_t)e * westride;
    int c0 = ct * 128;
    int lane = tid & 63, w = tid >> 6;
    int rl = lane & 15, kg = lane >> 4;

    int items[G];
#pragma unroll
    for (int j = 0; j < G; ++j) items[j] = perm[gid * G + j];

    __shared__ __align__(16) u16 As[ROWS * 72];
    __shared__ __align__(16) u16 Bs[128 * 72];

    f32x4 acc[MT][2];
#pragma unroll
    for (int mt = 0; mt < MT; ++mt)
#pragma unroll
        for (int j = 0; j < 2; ++j) acc[mt][j] = (f32x4){0.f, 0.f, 0.f, 0.f};

    for (int k0 = 0; k0 < 512; k0 += 64) {
        for (int idx = tid; idx < ROWS * 8; idx += 256) {
            int r = idx >> 3, q = idx & 7;
            int4 v = {0, 0, 0, 0};
            if (r < MR) {
                int j = r / 65;
                int id = items[j];
                if (id >= 0) {
                    int tok = r - j * 65;
                    v = *(const int4*)&A[((size_t)id * NTOK + tok) * 512 + k0 + q * 8];
                }
            }
            *(int4*)&As[r * 72 + q * 8] = v;
        }
        for (int idx = tid; idx < 1024; idx += 256) {
            int c = idx >> 3, q = idx & 7;
            *(int4*)&Bs[c * 72 + q * 8] = *(const int4*)&Wt[(size_t)(c0 + c) * 512 + k0 + q * 8];
        }
        __syncthreads();
#pragma unroll
        for (int ks = 0; ks < 2; ++ks) {
            bf16x8 bv0 = *(const bf16x8*)&Bs[((w * 2) * 16 + rl) * 72 + ks * 32 + kg * 8];
            bf16x8 bv1 = *(const bf16x8*)&Bs[((w * 2 + 1) * 16 + rl) * 72 + ks * 32 + kg * 8];
#pragma unroll
            for (int mt = 0; mt < MT; ++mt) {
                bf16x8 av = *(const bf16x8*)&As[(mt * 16 + rl) * 72 + ks * 32 + kg * 8];
                acc[mt][0] = __builtin_amdgcn_mfma_f32_16x16x32_bf16(av, bv0, acc[mt][0], 0, 0, 0);
                acc[mt][1] = __builtin_amdgcn_mfma_f32_16x16x32_bf16(av, bv1, acc[mt][1], 0, 0, 0);
            }
        }
        __syncthreads();
    }

    int rh = lane >> 4;
#pragma unroll
    for (int mt = 0; mt < MT; ++mt)
#pragma unroll
        for (int j = 0; j < 2; ++j)
#pragma unroll
            for (int r = 0; r < 4; ++r) {
                int row = mt * 16 + rh * 4 + r;
                if (row >= MR) continue;
                int ji = row / 65;
                int id = items[ji];
                if (id < 0) continue;
                int tok = row - ji * 65;
                int c = c0 + (w * 2 + j) * 16 + rl;
                float v = acc[mt][j][r];
                size_t o = ((size_t)id * NTOK + tok) * N + c;
                if (OP == 0) {
                    ((u16*)Cptr)[o] = f2bf(v);
                } else if (OP == 1) {
                    float* C = (float*)Cptr;
                    C[o] += v + Bbase[(size_t)e * bestride + c];
                } else {
                    float vb = v + Bbase[(size_t)e * bestride + c];
                    float gl = vb * 0.5f * (1.f + erff(vb * 0.70710678118f));
                    ((u16*)Cptr)[o] = f2bf(gl);
                }
            }
}

// ---------------------------------------------------------------------------
// Fallback MFMA GEMM (fp32 weights, per-item) — used if ws too small.
// ---------------------------------------------------------------------------
template <int N, int OP>
__global__ __launch_bounds__(256) void mgemm_k(const u16* __restrict__ A,
                                               const float* __restrict__ Wbase,
                                               const float* __restrict__ Bbase,
                                               void* __restrict__ Cptr,
                                               const int* __restrict__ top1,
                                               int westride, int bestride) {
    int ct = blockIdx.x, b = blockIdx.y, tid = threadIdx.x;
    int e = top1[b];
    const float* W = Wbase + (size_t)e * westride + ct * 128;
    int c0 = ct * 128;
    int lane = tid & 63, w = tid >> 6;

    __shared__ __align__(16) u16 As[4][80][8];
    __shared__ __align__(16) u16 Bs[4][128][8];

    const u16* Ab = A + (size_t)b * NTOK * 512;

    f32x4 acc[5][2];
#pragma unroll
    for (int mt = 0; mt < 5; ++mt)
#pragma unroll
        for (int j = 0; j < 2; ++j) acc[mt][j] = (f32x4){0.f, 0.f, 0.f, 0.f};

    int rl = lane & 15, kg = lane >> 4;

    for (int k0 = 0; k0 < 512; k0 += 32) {
        for (int idx = tid; idx < 320; idx += 256) {
            int r = idx >> 2, q = idx & 3;
            int4 v = {0, 0, 0, 0};
            if (r < NTOK) v = *(const int4*)&Ab[(size_t)r * 512 + k0 + q * 8];
            *(int4*)&As[q][r][0] = v;
        }
        for (int idx = tid; idx < 512; idx += 256) {
            int c = idx & 127, kq = idx >> 7;
            u16 tmp[8];
#pragma unroll
            for (int j = 0; j < 8; ++j)
                tmp[j] = f2bf(W[(size_t)(k0 + kq * 8 + j) * N + c]);
            *(int4*)&Bs[kq][c][0] = *(int4*)tmp;
        }
        __syncthreads();
        bf16x8 bfr0 = *(const bf16x8*)&Bs[kg][(w * 2) * 16 + rl][0];
        bf16x8 bfr1 = *(const bf16x8*)&Bs[kg][(w * 2 + 1) * 16 + rl][0];
#pragma unroll
        for (int mt = 0; mt < 5; ++mt) {
            bf16x8 av = *(const bf16x8*)&As[kg][mt * 16 + rl][0];
            acc[mt][0] = __builtin_amdgcn_mfma_f32_16x16x32_bf16(av, bfr0, acc[mt][0], 0, 0, 0);
            acc[mt][1] = __builtin_amdgcn_mfma_f32_16x16x32_bf16(av, bfr1, acc[mt][1], 0, 0, 0);
        }
        __syncthreads();
    }

    int rh = lane >> 4;
#pragma unroll
    for (int mt = 0; mt < 5; ++mt)
#pragma unroll
        for (int j = 0; j < 2; ++j)
#pragma unroll
            for (int r = 0; r < 4; ++r) {
                int m = mt * 16 + rh * 4 + r;
                if (m >= NTOK) continue;
                int c = c0 + (w * 2 + j) * 16 + rl;
                float v = acc[mt][j][r];
                size_t o = ((size_t)b * NTOK + m) * N + c;
                if (OP == 0) {
                    ((u16*)Cptr)[o] = f2bf(v);
                } else if (OP == 1) {
                    float* C = (float*)Cptr;
                    C[o] += v + Bbase[(size_t)e * bestride + c];
                } else {
                    float vb = v + Bbase[(size_t)e * bestride + c];
                    float gl = vb * 0.5f * (1.f + erff(vb * 0.70710678118f));
                    ((u16*)Cptr)[o] = f2bf(gl);
                }
            }
}

// ---------------------------------------------------------------------------
// MFMA attention: block per (b,h), 4 waves. QK^T / softmax-in-reg / PV.
// ---------------------------------------------------------------------------
#define ATT_LDS (23040 / 2 + 8320 / 2 + 12288 / 2)
__global__ __launch_bounds__(256) void attn2_k(const u16* __restrict__ qkv,
                                               u16* __restrict__ o) {
    int h = blockIdx.x, b = blockIdx.y, tid = threadIdx.x;
    __shared__ __align__(16) u16 smem[ATT_LDS];
    u16* Qs = smem;                    // [80][72]
    u16* Ks = smem + 80 * 72;          // [80][72]
    u16* Ps = smem;                    // [80][96]  (aliases Qs+Ks after barrier)
    u16* Vs = smem + 2 * 80 * 72;      // [65][64]
    u16* Vt = Vs + 65 * 64;            // [64][96]

    const u16* base = qkv + (size_t)b * NTOK * 1536 + h * 64;

    for (int idx = tid; idx < 640; idx += 256) {
        int r = idx >> 3, q = idx & 7;
        int4 vq = {0, 0, 0, 0}, vk = {0, 0, 0, 0};
        if (r < NTOK) {
            vq = *(const int4*)&base[(size_t)r * 1536 + q * 8];
            vk = *(const int4*)&base[(size_t)r * 1536 + 512 + q * 8];
        }
        *(int4*)&Qs[r * 72 + q * 8] = vq;
        *(int4*)&Ks[r * 72 + q * 8] = vk;
    }
    for (int idx = tid; idx < 520; idx += 256) {
        int r = idx >> 3, q = idx & 7;
        *(int4*)&Vs[r * 64 + q * 8] = *(const int4*)&base[(size_t)r * 1536 + 1024 + q * 8];
    }
    __syncthreads();

    int lane = tid & 63, w = tid >> 6;
    int rl = lane & 15, kg = lane >> 4, g = lane >> 4;

    f32x4 acc[2][5];
#pragma unroll
    for (int mi = 0; mi < 2; ++mi)
#pragma unroll
        for (int nt = 0; nt < 5; ++nt) acc[mi][nt] = (f32x4){0.f, 0.f, 0.f, 0.f};

#pragma unroll
    for (int mi = 0; mi < 2; ++mi) {
        if (mi == 1 && w != 0) continue;
        int mt = (mi == 0) ? w : 4;
        bf16x8 av0 = *(const bf16x8*)&Qs[(mt * 16 + rl) * 72 + kg * 8];
        bf16x8 av1 = *(const bf16x8*)&Qs[(mt * 16 + rl) * 72 + 32 + kg * 8];
#pragma unroll
        for (int nt = 0; nt < 5; ++nt) {
            bf16x8 bv0 = *(const bf16x8*)&Ks[(nt * 16 + rl) * 72 + kg * 8];
            bf16x8 bv1 = *(const bf16x8*)&Ks[(nt * 16 + rl) * 72 + 32 + kg * 8];
            acc[mi][nt] = __builtin_amdgcn_mfma_f32_16x16x32_bf16(av0, bv0, acc[mi][nt], 0, 0, 0);
            acc[mi][nt] = __builtin_amdgcn_mfma_f32_16x16x32_bf16(av1, bv1, acc[mi][nt], 0, 0, 0);
        }
    }

    for (int idx = tid; idx < 768; idx += 256) {
        int d = idx & 63, kq = idx >> 6;
        u16 tmp[8];
#pragma unroll
        for (int j = 0; j < 8; ++j) {
            int k = kq * 8 + j;
            tmp[j] = (k < NTOK) ? Vs[k * 64 + d] : (u16)0;
        }
        *(int4*)&Vt[d * 96 + kq * 8] = *(int4*)tmp;
    }

#pragma unroll
    for (int mi = 0; mi < 2; ++mi) {
        if (mi == 1 && w != 0) continue;
#pragma unroll
        for (int r = 0; r < 4; ++r) {
            float m = -3.0e38f;
#pragma unroll
            for (int nt = 0; nt < 5; ++nt) {
                float s = acc[mi][nt][r] * 0.125f;
                if (nt * 16 + rl >= NTOK) s = -3.0e38f;
                acc[mi][nt][r] = s;
                m = fmaxf(m, s);
            }
            m = fmaxf(m, __shfl_xor(m, 1));
            m = fmaxf(m, __shfl_xor(m, 2));
            m = fmaxf(m, __shfl_xor(m, 4));
            m = fmaxf(m, __shfl_xor(m, 8));
            float sum = 0.f;
#pragma unroll
            for (int nt = 0; nt < 5; ++nt) {
                float p = expf(acc[mi][nt][r] - m);
                acc[mi][nt][r] = p;
                sum += p;
            }
            sum += __shfl_xor(sum, 1);
            sum += __shfl_xor(sum, 2);
            sum += __shfl_xor(sum, 4);
            sum += __shfl_xor(sum, 8);
            float inv = 1.f / sum;
#pragma unroll
            for (int nt = 0; nt < 5; ++nt) acc[mi][nt][r] *= inv;
        }
    }
    __syncthreads();

#pragma unroll
    for (int mi = 0; mi < 2; ++mi) {
        if (mi == 1 && w != 0) continue;
        int mt = (mi == 0) ? w : 4;
#pragma unroll
        for (int nt = 0; nt < 5; ++nt)
#pragma unroll
            for (int r = 0; r < 4; ++r)
                Ps[(mt * 16 + g * 4 + r) * 96 + nt * 16 + rl] = f2bf(acc[mi][nt][r]);
    }
    for (int idx = tid; idx < 160; idx += 256) {
        int r = idx >> 1, hf = idx & 1;
        *(int4*)&Ps[r * 96 + 80 + hf * 8] = (int4){0, 0, 0, 0};
    }
    __syncthreads();

#pragma unroll
    for (int mi = 0; mi < 2; ++mi) {
        if (mi == 1 && w != 0) continue;
        int mt = (mi == 0) ? w : 4;
#pragma unroll
        for (int dt = 0; dt < 4; ++dt) {
            f32x4 oa = {0.f, 0.f, 0.f, 0.f};
#pragma unroll
            for (int s2 = 0; s2 < 3; ++s2) {
                bf16x8 av = *(const bf16x8*)&Ps[(mt * 16 + rl) * 96 + s2 * 32 + kg * 8];
                bf16x8 bv = *(const bf16x8*)&Vt[(dt * 16 + rl) * 96 + s2 * 32 + kg * 8];
                oa = __builtin_amdgcn_mfma_f32_16x16x32_bf16(av, bv, oa, 0, 0, 0);
            }
#pragma unroll
            for (int r = 0; r < 4; ++r) {
                int row = mt * 16 + g * 4 + r;
                if (row < NTOK)
                    o[((size_t)b * NTOK + row) * DIM + h * 64 + dt * 16 + rl] = f2bf(oa[r]);
            }
        }
    }
}

// ---------------------------------------------------------------------------
// Final LN (row 0) + head (fp32)
// ---------------------------------------------------------------------------
__global__ __launch_bounds__(64) void final_k(const float* __restrict__ t,
                                              const float* __restrict__ fg,
                                              const float* __restrict__ fb,
                                              const float* __restrict__ hw,
                                              const float* __restrict__ hb,
                                              const int* __restrict__ top1,
                                              float* __restrict__ out) {
    int b = blockIdx.x, lane = threadIdx.x;
    int e = top1[b];
    const float* row = t + (size_t)b * NTOK * DIM;
    float v[8], s = 0.f, q = 0.f;
#pragma unroll
    for (int ii = 0; ii < 8; ++ii) {
        v[ii] = row[ii * 64 + lane];
        s += v[ii];
        q += v[ii] * v[ii];
    }
    for (int off = 32; off > 0; off >>= 1) {
        s += __shfl_xor(s, off);
        q += __shfl_xor(q, off);
    }
    float mean = s * (1.f / DIM);
    float var = q * (1.f / DIM) - mean * mean;
    float rs = rsqrtf(var + 1e-5f);
    float nv[8];
#pragma unroll
    for (int ii = 0; ii < 8; ++ii) {
        int d = ii * 64 + lane;
        nv[ii] = (v[ii] - mean) * rs * fg[e * DIM + d] + fb[e * DIM + d];
    }
    for (int c = 0; c < NCLS; ++c) {
        float p = 0.f;
#pragma unroll
        for (int ii = 0; ii < 8; ++ii) {
            int d = ii * 64 + lane;
            p = fmaf(nv[ii], hw[(size_t)e * DIM * NCLS + d * NCLS + c], p);
        }
        for (int off = 32; off > 0; off >>= 1) p += __shfl_xor(p, off);
        if (lane == 0) out[b * NCLS + c] = p + hb[e * NCLS + c];
    }
}

// ---------------------------------------------------------------------------
extern "C" void kernel_launch(void* const* d_in, const int* in_sizes, int n_in,
                              void* d_out, int out_size, void* d_ws, size_t ws_size,
                              hipStream_t stream) {
    const float* x       = (const float*)d_in[0];
    const float* gate_w  = (const float*)d_in[1];
    const float* gate_b  = (const float*)d_in[2];
    const float* pln1_g  = (const float*)d_in[3];
    const float* pln1_b  = (const float*)d_in[4];
    const float* patch_w = (const float*)d_in[5];
    const float* patch_b = (const float*)d_in[6];
    const float* pln2_g  = (const float*)d_in[7];
    const float* pln2_b  = (const float*)d_in[8];
    const float* cls_tok = (const float*)d_in[9];
    const float* pos_emb = (const float*)d_in[10];
    const float* aln_g   = (const float*)d_in[11];
    const float* aln_b   = (const float*)d_in[12];
    const float* qkv_w   = (const float*)d_in[13];
    const float* out_w   = (const float*)d_in[14];
    const float* out_b   = (const float*)d_in[15];
    const float* fln_g   = (const float*)d_in[16];
    const float* fln_b   = (const float*)d_in[17];
    const float* ff1_w   = (const float*)d_in[18];
    const float* ff1_b   = (const float*)d_in[19];
    const float* ff2_w   = (const float*)d_in[20];
    const float* ff2_b   = (const float*)d_in[21];
    const float* final_g = (const float*)d_in[22];
    const float* final_b = (const float*)d_in[23];
    const float* head_w  = (const float*)d_in[24];
    const float* head_b  = (const float*)d_in[25];
    float* out = (float*)d_out;

    // Workspace layout
    int* top1 = (int*)d_ws;                                  // 128 ints
    float* t  = (float*)((char*)d_ws + 1024);                // fp32 [B,65,512]
    u16* g16  = (u16*)(t + (size_t)BATCH * NTOK * DIM);      // bf16 [B,65,512]
    u16* qb16 = g16 + (size_t)BATCH * NTOK * DIM;            // bf16 [B,65,1536]
    u16* wq_t = qb16 + (size_t)BATCH * NTOK * 1536;          // bf16 [48][1536][512]
    u16* wo_t = wq_t + (size_t)48 * 1536 * 512;              // bf16 [48][512][512]
    u16* w1_t = wo_t + (size_t)48 * 512 * 512;
    u16* w2_t = w1_t + (size_t)48 * 512 * 512;
    int* perm2 = (int*)(w2_t + (size_t)48 * 512 * 512);      // 136
    int* gexp2 = perm2 + 136;                                // 68
    int* perm4 = gexp2 + 68;                                 // 152
    int* gexp4 = perm4 + 152;                                // 38

    size_t need = (size_t)((char*)(gexp4 + 38) - (char*)d_ws);
    bool preconv = ws_size >= need;

    gate_k<<<BATCH, 256, 0, stream>>>(x, gate_w, gate_b, top1);
    route_k<<<1, 256, 0, stream>>>(top1, perm2, gexp2, perm4, gexp4);
    patch_k<<<dim3(NTOK, BATCH), 256, 0, stream>>>(x, pln1_g, pln1_b, patch_w, patch_b,
                                                   pln2_g, pln2_b, cls_tok, pos_emb, top1, t);
    if (preconv) {
        wconv_k<<<dim3(48, 16, 48), 256, 0, stream>>>(qkv_w, wq_t, 1536);
        wconv_k<<<dim3(16, 16, 48), 256, 0, stream>>>(out_w, wo_t, 512);
        wconv_k<<<dim3(16, 16, 48), 256, 0, stream>>>(ff1_w, w1_t, 512);
        wconv_k<<<dim3(16, 16, 48), 256, 0, stream>>>(ff2_w, w2_t, 512);
    }

    for (int l = 0; l < DEPTH; ++l) {
        ln_k<<<dim3(NTOK, BATCH), 256, 0, stream>>>(t, g16, aln_g + l * DIM, aln_b + l * DIM,
                                                    top1, DEPTH * DIM);
        if (preconv)
            mgemm3_k<1536, 0, 4><<<dim3(12, 38), 256, 0, stream>>>(
                g16, wq_t + (size_t)l * 1536 * 512, nullptr, qb16, perm4, gexp4,
                DEPTH * 512 * 1536, 0);
        else
            mgemm_k<1536, 0><<<dim3(12, BATCH), 256, 0, stream>>>(
                g16, qkv_w + (size_t)l * 512 * 1536, nullptr, qb16, top1,
                DEPTH * 512 * 1536, 0);
        attn2_k<<<dim3(HEADS, BATCH), 256, 0, stream>>>(qb16, g16);
        if (preconv) {
            mgemm3_k<512, 1, 2><<<dim3(4, 68), 256, 0, stream>>>(
                g16, wo_t + (size_t)l * 512 * 512, out_b + l * DIM, t, perm2, gexp2,
                DEPTH * 512 * 512, DEPTH * DIM);
        } else {
            mgemm_k<512, 1><<<dim3(4, BATCH), 256, 0, stream>>>(
                g16, out_w + (size_t)l * 512 * 512, out_b + l * DIM, t, top1,
                DEPTH * 512 * 512, DEPTH * DIM);
        }
        ln_k<<<dim3(NTOK, BATCH), 256, 0, stream>>>(t, g16, fln_g + l * DIM, fln_b + l * DIM,
                                                    top1, DEPTH * DIM);
        if (preconv) {
            mgemm3_k<512, 2, 2><<<dim3(4, 68), 256, 0, stream>>>(
                g16, w1_t + (size_t)l * 512 * 512, ff1_b + l * DIM, qb16, perm2, gexp2,
                DEPTH * 512 * 512, DEPTH * DIM);
            mgemm3_k<512, 1, 2><<<dim3(4, 68), 256, 0, stream>>>(
                qb16, w2_t + (size_t)l * 512 * 512, ff2_b + l * DIM, t, perm2, gexp2,
                DEPTH * 512 * 512, DEPTH * DIM);
        } else {
            mgemm_k<512, 2><<<dim3(4, BATCH), 256, 0, stream>>>(
                g16, ff1_w + (size_t)l * 512 * 512, ff1_b + l * DIM, qb16, top1,
                DEPTH * 512 * 512, DEPTH * DIM);
            mgemm_k<512, 1><<<dim3(4, BATCH), 256, 0, stream>>>(
                qb16, ff2_w + (size_t)l * 512 * 512, ff2_b + l * DIM, t, top1,
                DEPTH * 512 * 512, DEPTH * DIM);
        }
    }
    final_k<<<BATCH, 64, 0, stream>>>(t, final_g, final_b, head_w, head_b, top1, out);
}

// Round 5
// 1434.454 us; speedup vs baseline: 1.4366x; 1.4366x over previous
//
#include <hip/hip_runtime.h>
#include <math.h>

#define EXPERTS 8
#define DEPTH 6
#define DIM 512
#define HEADS 8
#define NCLS 10
#define BATCH 128
#define PD 48
#define NTOK 65

typedef __attribute__((ext_vector_type(4))) float f32x4;
typedef __attribute__((ext_vector_type(8))) __bf16 bf16x8;
typedef unsigned short u16;

__device__ inline u16 f2bf(float f) {
    union { float f; unsigned u; } v; v.f = f;
    unsigned r = v.u + 0x7FFFu + ((v.u >> 16) & 1u);
    return (u16)(r >> 16);
}
__device__ inline float bf2f(u16 s) {
    union { unsigned u; float f; } v; v.u = ((unsigned)s) << 16;
    return v.f;
}

// ---------------------------------------------------------------------------
// Gate (exact fp32 — routing must not flip)
// ---------------------------------------------------------------------------
__global__ __launch_bounds__(256) void gate_k(const float* __restrict__ x,
                                              const float* __restrict__ gw,
                                              const float* __restrict__ gb,
                                              int* __restrict__ top1) {
    int b = blockIdx.x, tid = threadIdx.x;
    const float* xb = x + (size_t)b * 3072;
    float acc[EXPERTS];
#pragma unroll
    for (int e = 0; e < EXPERTS; ++e) acc[e] = 0.f;
    for (int i = tid; i < 3072; i += 256) {
        float xv = xb[i];
#pragma unroll
        for (int e = 0; e < EXPERTS; ++e)
            acc[e] = fmaf(xv, gw[(size_t)e * 3072 + i], acc[e]);
    }
    __shared__ float red[256];
    __shared__ float logits[EXPERTS];
    for (int e = 0; e < EXPERTS; ++e) {
        red[tid] = acc[e];
        __syncthreads();
        for (int s = 128; s > 0; s >>= 1) {
            if (tid < s) red[tid] += red[tid + s];
            __syncthreads();
        }
        if (tid == 0) logits[e] = red[0] + gb[e];
        __syncthreads();
    }
    if (tid == 0) {
        int best = 0;
        float bv = logits[0];
        for (int e = 1; e < EXPERTS; ++e)
            if (logits[e] > bv) { bv = logits[e]; best = e; }
        top1[b] = best;
    }
}

// ---------------------------------------------------------------------------
// Patch embed (fp32, writes residual stream t)
// ---------------------------------------------------------------------------
__global__ __launch_bounds__(256) void patch_k(const float* __restrict__ x,
                                               const float* __restrict__ pln1_g,
                                               const float* __restrict__ pln1_b,
                                               const float* __restrict__ patch_w,
                                               const float* __restrict__ patch_b,
                                               const float* __restrict__ pln2_g,
                                               const float* __restrict__ pln2_b,
                                               const float* __restrict__ cls_tok,
                                               const float* __restrict__ pos_emb,
                                               const int* __restrict__ top1,
                                               float* __restrict__ t) {
    int n = blockIdx.x, b = blockIdx.y, tid = threadIdx.x;
    int e = top1[b];
    float* trow = t + ((size_t)b * NTOK + n) * DIM;
    const float* pe = pos_emb + ((size_t)e * NTOK + n) * DIM;

    if (n == 0) {
        for (int d = tid; d < DIM; d += 256)
            trow[d] = cls_tok[e * DIM + d] + pe[d];
        return;
    }
    int pi = n - 1, h = pi >> 3, w = pi & 7;
    __shared__ float pv[PD];
    __shared__ float red[256];
    if (tid < PD) {
        int p1 = tid / 12, rem = tid % 12, p2 = rem / 3, c = rem % 3;
        pv[tid] = x[((size_t)b * 3 + c) * 1024 + (h * 4 + p1) * 32 + (w * 4 + p2)];
    }
    __syncthreads();
    float m = 0.f, q = 0.f;
    for (int j = 0; j < PD; ++j) { float v = pv[j]; m += v; q += v * v; }
    m *= (1.f / PD);
    q = q * (1.f / PD) - m * m;
    float rs = rsqrtf(q + 1e-5f);
    __syncthreads();
    if (tid < PD)
        pv[tid] = (pv[tid] - m) * rs * pln1_g[e * PD + tid] + pln1_b[e * PD + tid];
    __syncthreads();

    float acc0 = patch_b[e * DIM + tid];
    float acc1 = patch_b[e * DIM + tid + 256];
    for (int j = 0; j < PD; ++j) {
        float v = pv[j];
        const float* wr = patch_w + ((size_t)e * PD + j) * DIM;
        acc0 = fmaf(v, wr[tid], acc0);
        acc1 = fmaf(v, wr[tid + 256], acc1);
    }
    red[tid] = acc0 + acc1;
    __syncthreads();
    for (int s = 128; s > 0; s >>= 1) {
        if (tid < s) red[tid] += red[tid + s];
        __syncthreads();
    }
    float S = red[0];
    __syncthreads();
    red[tid] = acc0 * acc0 + acc1 * acc1;
    __syncthreads();
    for (int s = 128; s > 0; s >>= 1) {
        if (tid < s) red[tid] += red[tid + s];
        __syncthreads();
    }
    float Q = red[0];
    float mean = S * (1.f / DIM);
    float var = Q * (1.f / DIM) - mean * mean;
    float rs2 = rsqrtf(var + 1e-5f);
    trow[tid]       = (acc0 - mean) * rs2 * pln2_g[e * DIM + tid]       + pln2_b[e * DIM + tid]       + pe[tid];
    trow[tid + 256] = (acc1 - mean) * rs2 * pln2_g[e * DIM + tid + 256] + pln2_b[e * DIM + tid + 256] + pe[tid + 256];
}

// ---------------------------------------------------------------------------
// Weight convert: fp32 [cnt][512][N] -> bf16 [cnt][N][512] (transpose).
// ---------------------------------------------------------------------------
__global__ __launch_bounds__(256) void wconv_k(const float* __restrict__ src,
                                               u16* __restrict__ dst, int N) {
    __shared__ float tile[32][33];
    int n0 = blockIdx.x * 32, k0 = blockIdx.y * 32, m = blockIdx.z;
    const float* s = src + (size_t)m * 512 * N;
    u16* d = dst + (size_t)m * 512 * N;
    int r = threadIdx.x >> 5, c = threadIdx.x & 31;
#pragma unroll
    for (int i = 0; i < 4; ++i)
        tile[r + i * 8][c] = s[(size_t)(k0 + r + i * 8) * N + n0 + c];
    __syncthreads();
#pragma unroll
    for (int i = 0; i < 4; ++i)
        d[(size_t)(n0 + r + i * 8) * 512 + k0 + c] = f2bf(tile[c][r + i * 8]);
}

// ---------------------------------------------------------------------------
// Fused LayerNorm + MFMA GEMM: C[65,N] = LN(t[b]) @ Wt (bf16, Wt[n][k]).
// grid (N/128, B), block 256 (4 waves), K-step 64, M=80 (5 m-tiles).
// Stats (mean/rstd per row) computed in-block via wave shuffles; LN applied
// during A staging (fp32 -> bf16), bitwise-matching the old ln_k formula.
// OP: 0 = store bf16 (qkv, no bias); 2 = bias + exact GELU -> bf16 (ff1)
// ---------------------------------------------------------------------------
template <int N, int OP>
__global__ __launch_bounds__(256) void lngemm_k(const float* __restrict__ T,
                                                const float* __restrict__ gbase,
                                                const float* __restrict__ bbase,
                                                const u16* __restrict__ Wtbase,
                                                const float* __restrict__ Bias,
                                                u16* __restrict__ C,
                                                const int* __restrict__ top1,
                                                int gestride, int westride,
                                                int bestride) {
    int ct = blockIdx.x, b = blockIdx.y, tid = threadIdx.x;
    int e = top1[b];
    const u16* Wt = Wtbase + (size_t)e * westride;
    const float* gamma = gbase + (size_t)e * gestride;
    const float* beta  = bbase + (size_t)e * gestride;
    int c0 = ct * 128;
    int lane = tid & 63, w = tid >> 6;
    int rl = lane & 15, kg = lane >> 4;

    __shared__ __align__(16) u16 As[80 * 72];
    __shared__ __align__(16) u16 Bs[128 * 72];
    __shared__ float mean_s[65];
    __shared__ float rstd_s[65];

    const float* Tb = T + (size_t)b * NTOK * 512;

    // zero-pad rows 65..79 once
    for (int idx = tid; idx < 135; idx += 256) {
        int r = 65 + idx / 9, q = idx % 9;
        *(int4*)&As[r * 72 + q * 8] = (int4){0, 0, 0, 0};
    }
    // per-row LN stats: wave w handles rows w, w+4, ...
    for (int r = w; r < NTOK; r += 4) {
        float s = 0.f, sq = 0.f;
#pragma unroll
        for (int ii = 0; ii < 8; ++ii) {
            float v = Tb[r * 512 + ii * 64 + lane];
            s += v;
            sq += v * v;
        }
#pragma unroll
        for (int off = 32; off > 0; off >>= 1) {
            s += __shfl_xor(s, off);
            sq += __shfl_xor(sq, off);
        }
        if (lane == 0) {
            float m = s * (1.f / DIM);
            mean_s[r] = m;
            rstd_s[r] = rsqrtf(sq * (1.f / DIM) - m * m + 1e-5f);
        }
    }
    __syncthreads();

    f32x4 acc[5][2];
#pragma unroll
    for (int mt = 0; mt < 5; ++mt)
#pragma unroll
        for (int j = 0; j < 2; ++j) acc[mt][j] = (f32x4){0.f, 0.f, 0.f, 0.f};

    for (int k0 = 0; k0 < 512; k0 += 64) {
        // A staging with fused LN: 65 rows x 16 float4 tasks
        for (int idx = tid; idx < 1040; idx += 256) {
            int r = idx >> 4, q = idx & 15;
            int k = k0 + q * 4;
            float4 v = *(const float4*)&Tb[r * 512 + k];
            float4 g4 = *(const float4*)&gamma[k];
            float4 b4 = *(const float4*)&beta[k];
            float m = mean_s[r], rs = rstd_s[r];
            u16 o4[4];
            o4[0] = f2bf((v.x - m) * rs * g4.x + b4.x);
            o4[1] = f2bf((v.y - m) * rs * g4.y + b4.y);
            o4[2] = f2bf((v.z - m) * rs * g4.z + b4.z);
            o4[3] = f2bf((v.w - m) * rs * g4.w + b4.w);
            *(int2*)&As[r * 72 + q * 4] = *(int2*)o4;
        }
        for (int idx = tid; idx < 1024; idx += 256) {
            int c = idx >> 3, q = idx & 7;
            *(int4*)&Bs[c * 72 + q * 8] = *(const int4*)&Wt[(size_t)(c0 + c) * 512 + k0 + q * 8];
        }
        __syncthreads();
#pragma unroll
        for (int ks = 0; ks < 2; ++ks) {
            bf16x8 bv0 = *(const bf16x8*)&Bs[((w * 2) * 16 + rl) * 72 + ks * 32 + kg * 8];
            bf16x8 bv1 = *(const bf16x8*)&Bs[((w * 2 + 1) * 16 + rl) * 72 + ks * 32 + kg * 8];
#pragma unroll
            for (int mt = 0; mt < 5; ++mt) {
                bf16x8 av = *(const bf16x8*)&As[(mt * 16 + rl) * 72 + ks * 32 + kg * 8];
                acc[mt][0] = __builtin_amdgcn_mfma_f32_16x16x32_bf16(av, bv0, acc[mt][0], 0, 0, 0);
                acc[mt][1] = __builtin_amdgcn_mfma_f32_16x16x32_bf16(av, bv1, acc[mt][1], 0, 0, 0);
            }
        }
        __syncthreads();
    }

    int rh = lane >> 4;
#pragma unroll
    for (int mt = 0; mt < 5; ++mt)
#pragma unroll
        for (int j = 0; j < 2; ++j)
#pragma unroll
            for (int r = 0; r < 4; ++r) {
                int m = mt * 16 + rh * 4 + r;
                if (m >= NTOK) continue;
                int c = c0 + (w * 2 + j) * 16 + rl;
                float v = acc[mt][j][r];
                size_t o = ((size_t)b * NTOK + m) * N + c;
                if (OP == 0) {
                    C[o] = f2bf(v);
                } else {
                    float vb = v + Bias[(size_t)e * bestride + c];
                    float gl = vb * 0.5f * (1.f + erff(vb * 0.70710678118f));
                    C[o] = f2bf(gl);
                }
            }
}

// ---------------------------------------------------------------------------
// MFMA GEMM, bf16 activations in (no LN): C = A @ Wt, OP=1: fp32 += acc+bias.
// grid (N/128, B), block 256, K-step 64, M=80.
// ---------------------------------------------------------------------------
template <int N, int OP>
__global__ __launch_bounds__(256) void mgemm2_k(const u16* __restrict__ A,
                                                const u16* __restrict__ Wtbase,
                                                const float* __restrict__ Bbase,
                                                void* __restrict__ Cptr,
                                                const int* __restrict__ top1,
                                                int westride, int bestride) {
    int ct = blockIdx.x, b = blockIdx.y, tid = threadIdx.x;
    int e = top1[b];
    const u16* Wt = Wtbase + (size_t)e * westride;
    int c0 = ct * 128;
    int lane = tid & 63, w = tid >> 6;
    int rl = lane & 15, kg = lane >> 4;

    __shared__ __align__(16) u16 As[80 * 72];
    __shared__ __align__(16) u16 Bs[128 * 72];

    const u16* Ab = A + (size_t)b * NTOK * 512;

    for (int idx = tid; idx < 135; idx += 256) {
        int r = 65 + idx / 9, q = idx % 9;
        *(int4*)&As[r * 72 + q * 8] = (int4){0, 0, 0, 0};
    }

    f32x4 acc[5][2];
#pragma unroll
    for (int mt = 0; mt < 5; ++mt)
#pragma unroll
        for (int j = 0; j < 2; ++j) acc[mt][j] = (f32x4){0.f, 0.f, 0.f, 0.f};

    for (int k0 = 0; k0 < 512; k0 += 64) {
        for (int idx = tid; idx < 520; idx += 256) {
            int r = idx >> 3, q = idx & 7;
            *(int4*)&As[r * 72 + q * 8] = *(const int4*)&Ab[(size_t)r * 512 + k0 + q * 8];
        }
        for (int idx = tid; idx < 1024; idx += 256) {
            int c = idx >> 3, q = idx & 7;
            *(int4*)&Bs[c * 72 + q * 8] = *(const int4*)&Wt[(size_t)(c0 + c) * 512 + k0 + q * 8];
        }
        __syncthreads();
#pragma unroll
        for (int ks = 0; ks < 2; ++ks) {
            bf16x8 bv0 = *(const bf16x8*)&Bs[((w * 2) * 16 + rl) * 72 + ks * 32 + kg * 8];
            bf16x8 bv1 = *(const bf16x8*)&Bs[((w * 2 + 1) * 16 + rl) * 72 + ks * 32 + kg * 8];
#pragma unroll
            for (int mt = 0; mt < 5; ++mt) {
                bf16x8 av = *(const bf16x8*)&As[(mt * 16 + rl) * 72 + ks * 32 + kg * 8];
                acc[mt][0] = __builtin_amdgcn_mfma_f32_16x16x32_bf16(av, bv0, acc[mt][0], 0, 0, 0);
                acc[mt][1] = __builtin_amdgcn_mfma_f32_16x16x32_bf16(av, bv1, acc[mt][1], 0, 0, 0);
            }
        }
        __syncthreads();
    }

    int rh = lane >> 4;
#pragma unroll
    for (int mt = 0; mt < 5; ++mt)
#pragma unroll
        for (int j = 0; j < 2; ++j)
#pragma unroll
            for (int r = 0; r < 4; ++r) {
                int m = mt * 16 + rh * 4 + r;
                if (m >= NTOK) continue;
                int c = c0 + (w * 2 + j) * 16 + rl;
                float v = acc[mt][j][r];
                size_t o = ((size_t)b * NTOK + m) * N + c;
                if (OP == 0) {
                    ((u16*)Cptr)[o] = f2bf(v);
                } else {
                    float* Cf = (float*)Cptr;
                    Cf[o] += v + Bbase[(size_t)e * bestride + c];
                }
            }
}

// ---------------------------------------------------------------------------
// MFMA attention: block per (b,h), 4 waves. QK^T / softmax-in-reg / PV.
// ---------------------------------------------------------------------------
#define ATT_LDS (23040 / 2 + 8320 / 2 + 12288 / 2)
__global__ __launch_bounds__(256) void attn2_k(const u16* __restrict__ qkv,
                                               u16* __restrict__ o) {
    int h = blockIdx.x, b = blockIdx.y, tid = threadIdx.x;
    __shared__ __align__(16) u16 smem[ATT_LDS];
    u16* Qs = smem;                    // [80][72]
    u16* Ks = smem + 80 * 72;          // [80][72]
    u16* Ps = smem;                    // [80][96]  (aliases Qs+Ks after barrier)
    u16* Vs = smem + 2 * 80 * 72;      // [65][64]
    u16* Vt = Vs + 65 * 64;            // [64][96]

    const u16* base = qkv + (size_t)b * NTOK * 1536 + h * 64;

    for (int idx = tid; idx < 640; idx += 256) {
        int r = idx >> 3, q = idx & 7;
        int4 vq = {0, 0, 0, 0}, vk = {0, 0, 0, 0};
        if (r < NTOK) {
            vq = *(const int4*)&base[(size_t)r * 1536 + q * 8];
            vk = *(const int4*)&base[(size_t)r * 1536 + 512 + q * 8];
        }
        *(int4*)&Qs[r * 72 + q * 8] = vq;
        *(int4*)&Ks[r * 72 + q * 8] = vk;
    }
    for (int idx = tid; idx < 520; idx += 256) {
        int r = idx >> 3, q = idx & 7;
        *(int4*)&Vs[r * 64 + q * 8] = *(const int4*)&base[(size_t)r * 1536 + 1024 + q * 8];
    }
    __syncthreads();

    int lane = tid & 63, w = tid >> 6;
    int rl = lane & 15, kg = lane >> 4, g = lane >> 4;

    f32x4 acc[2][5];
#pragma unroll
    for (int mi = 0; mi < 2; ++mi)
#pragma unroll
        for (int nt = 0; nt < 5; ++nt) acc[mi][nt] = (f32x4){0.f, 0.f, 0.f, 0.f};

#pragma unroll
    for (int mi = 0; mi < 2; ++mi) {
        if (mi == 1 && w != 0) continue;
        int mt = (mi == 0) ? w : 4;
        bf16x8 av0 = *(const bf16x8*)&Qs[(mt * 16 + rl) * 72 + kg * 8];
        bf16x8 av1 = *(const bf16x8*)&Qs[(mt * 16 + rl) * 72 + 32 + kg * 8];
#pragma unroll
        for (int nt = 0; nt < 5; ++nt) {
            bf16x8 bv0 = *(const bf16x8*)&Ks[(nt * 16 + rl) * 72 + kg * 8];
            bf16x8 bv1 = *(const bf16x8*)&Ks[(nt * 16 + rl) * 72 + 32 + kg * 8];
            acc[mi][nt] = __builtin_amdgcn_mfma_f32_16x16x32_bf16(av0, bv0, acc[mi][nt], 0, 0, 0);
            acc[mi][nt] = __builtin_amdgcn_mfma_f32_16x16x32_bf16(av1, bv1, acc[mi][nt], 0, 0, 0);
        }
    }

    for (int idx = tid; idx < 768; idx += 256) {
        int d = idx & 63, kq = idx >> 6;
        u16 tmp[8];
#pragma unroll
        for (int j = 0; j < 8; ++j) {
            int k = kq * 8 + j;
            tmp[j] = (k < NTOK) ? Vs[k * 64 + d] : (u16)0;
        }
        *(int4*)&Vt[d * 96 + kq * 8] = *(int4*)tmp;
    }

#pragma unroll
    for (int mi = 0; mi < 2; ++mi) {
        if (mi == 1 && w != 0) continue;
#pragma unroll
        for (int r = 0; r < 4; ++r) {
            float m = -3.0e38f;
#pragma unroll
            for (int nt = 0; nt < 5; ++nt) {
                float s = acc[mi][nt][r] * 0.125f;
                if (nt * 16 + rl >= NTOK) s = -3.0e38f;
                acc[mi][nt][r] = s;
                m = fmaxf(m, s);
            }
            m = fmaxf(m, __shfl_xor(m, 1));
            m = fmaxf(m, __shfl_xor(m, 2));
            m = fmaxf(m, __shfl_xor(m, 4));
            m = fmaxf(m, __shfl_xor(m, 8));
            float sum = 0.f;
#pragma unroll
            for (int nt = 0; nt < 5; ++nt) {
                float p = expf(acc[mi][nt][r] - m);
                acc[mi][nt][r] = p;
                sum += p;
            }
            sum += __shfl_xor(sum, 1);
            sum += __shfl_xor(sum, 2);
            sum += __shfl_xor(sum, 4);
            sum += __shfl_xor(sum, 8);
            float inv = 1.f / sum;
#pragma unroll
            for (int nt = 0; nt < 5; ++nt) acc[mi][nt][r] *= inv;
        }
    }
    __syncthreads();

#pragma unroll
    for (int mi = 0; mi < 2; ++mi) {
        if (mi == 1 && w != 0) continue;
        int mt = (mi == 0) ? w : 4;
#pragma unroll
        for (int nt = 0; nt < 5; ++nt)
#pragma unroll
            for (int r = 0; r < 4; ++r)
                Ps[(mt * 16 + g * 4 + r) * 96 + nt * 16 + rl] = f2bf(acc[mi][nt][r]);
    }
    for (int idx = tid; idx < 160; idx += 256) {
        int r = idx >> 1, hf = idx & 1;
        *(int4*)&Ps[r * 96 + 80 + hf * 8] = (int4){0, 0, 0, 0};
    }
    __syncthreads();

#pragma unroll
    for (int mi = 0; mi < 2; ++mi) {
        if (mi == 1 && w != 0) continue;
        int mt = (mi == 0) ? w : 4;
#pragma unroll
        for (int dt = 0; dt < 4; ++dt) {
            f32x4 oa = {0.f, 0.f, 0.f, 0.f};
#pragma unroll
            for (int s2 = 0; s2 < 3; ++s2) {
                bf16x8 av = *(const bf16x8*)&Ps[(mt * 16 + rl) * 96 + s2 * 32 + kg * 8];
                bf16x8 bv = *(const bf16x8*)&Vt[(dt * 16 + rl) * 96 + s2 * 32 + kg * 8];
                oa = __builtin_amdgcn_mfma_f32_16x16x32_bf16(av, bv, oa, 0, 0, 0);
            }
#pragma unroll
            for (int r = 0; r < 4; ++r) {
                int row = mt * 16 + g * 4 + r;
                if (row < NTOK)
                    o[((size_t)b * NTOK + row) * DIM + h * 64 + dt * 16 + rl] = f2bf(oa[r]);
            }
        }
    }
}

// ---------------------------------------------------------------------------
// Final LN (row 0) + head (fp32)
// ---------------------------------------------------------------------------
__global__ __launch_bounds__(64) void final_k(const float* __restrict__ t,
                                              const float* __restrict__ fg,
                                              const float* __restrict__ fb,
                                              const float* __restrict__ hw,
                                              const float* __restrict__ hb,
                                              const int* __restrict__ top1,
                                              float* __restrict__ out) {
    int b = blockIdx.x, lane = threadIdx.x;
    int e = top1[b];
    const float* row = t + (size_t)b * NTOK * DIM;
    float v[8], s = 0.f, q = 0.f;
#pragma unroll
    for (int ii = 0; ii < 8; ++ii) {
        v[ii] = row[ii * 64 + lane];
        s += v[ii];
        q += v[ii] * v[ii];
    }
    for (int off = 32; off > 0; off >>= 1) {
        s += __shfl_xor(s, off);
        q += __shfl_xor(q, off);
    }
    float mean = s * (1.f / DIM);
    float var = q * (1.f / DIM) - mean * mean;
    float rs = rsqrtf(var + 1e-5f);
    float nv[8];
#pragma unroll
    for (int ii = 0; ii < 8; ++ii) {
        int d = ii * 64 + lane;
        nv[ii] = (v[ii] - mean) * rs * fg[e * DIM + d] + fb[e * DIM + d];
    }
    for (int c = 0; c < NCLS; ++c) {
        float p = 0.f;
#pragma unroll
        for (int ii = 0; ii < 8; ++ii) {
            int d = ii * 64 + lane;
            p = fmaf(nv[ii], hw[(size_t)e * DIM * NCLS + d * NCLS + c], p);
        }
        for (int off = 32; off > 0; off >>= 1) p += __shfl_xor(p, off);
        if (lane == 0) out[b * NCLS + c] = p + hb[e * NCLS + c];
    }
}

// ---------------------------------------------------------------------------
extern "C" void kernel_launch(void* const* d_in, const int* in_sizes, int n_in,
                              void* d_out, int out_size, void* d_ws, size_t ws_size,
                              hipStream_t stream) {
    const float* x       = (const float*)d_in[0];
    const float* gate_w  = (const float*)d_in[1];
    const float* gate_b  = (const float*)d_in[2];
    const float* pln1_g  = (const float*)d_in[3];
    const float* pln1_b  = (const float*)d_in[4];
    const float* patch_w = (const float*)d_in[5];
    const float* patch_b = (const float*)d_in[6];
    const float* pln2_g  = (const float*)d_in[7];
    const float* pln2_b  = (const float*)d_in[8];
    const float* cls_tok = (const float*)d_in[9];
    const float* pos_emb = (const float*)d_in[10];
    const float* aln_g   = (const float*)d_in[11];
    const float* aln_b   = (const float*)d_in[12];
    const float* qkv_w   = (const float*)d_in[13];
    const float* out_w   = (const float*)d_in[14];
    const float* out_b   = (const float*)d_in[15];
    const float* fln_g   = (const float*)d_in[16];
    const float* fln_b   = (const float*)d_in[17];
    const float* ff1_w   = (const float*)d_in[18];
    const float* ff1_b   = (const float*)d_in[19];
    const float* ff2_w   = (const float*)d_in[20];
    const float* ff2_b   = (const float*)d_in[21];
    const float* final_g = (const float*)d_in[22];
    const float* final_b = (const float*)d_in[23];
    const float* head_w  = (const float*)d_in[24];
    const float* head_b  = (const float*)d_in[25];
    float* out = (float*)d_out;

    // Workspace layout (ws is ~604 MB per harness fill counters; need ~220 MB)
    int* top1 = (int*)d_ws;                                  // 128 ints
    float* t  = (float*)((char*)d_ws + 1024);                // fp32 [B,65,512]
    u16* g16  = (u16*)(t + (size_t)BATCH * NTOK * DIM);      // bf16 [B,65,512]  (attn out)
    u16* qb16 = g16 + (size_t)BATCH * NTOK * DIM;            // bf16 [B,65,1536] (qkv out)
    u16* hb16 = qb16 + (size_t)BATCH * NTOK * 1536;          // bf16 [B,65,512]  (ff1 out)
    u16* wq_t = hb16 + (size_t)BATCH * NTOK * DIM;           // bf16 [48][1536][512]
    u16* wo_t = wq_t + (size_t)48 * 1536 * 512;              // bf16 [48][512][512]
    u16* w1_t = wo_t + (size_t)48 * 512 * 512;
    u16* w2_t = w1_t + (size_t)48 * 512 * 512;

    gate_k<<<BATCH, 256, 0, stream>>>(x, gate_w, gate_b, top1);
    patch_k<<<dim3(NTOK, BATCH), 256, 0, stream>>>(x, pln1_g, pln1_b, patch_w, patch_b,
                                                   pln2_g, pln2_b, cls_tok, pos_emb, top1, t);
    wconv_k<<<dim3(48, 16, 48), 256, 0, stream>>>(qkv_w, wq_t, 1536);
    wconv_k<<<dim3(16, 16, 48), 256, 0, stream>>>(out_w, wo_t, 512);
    wconv_k<<<dim3(16, 16, 48), 256, 0, stream>>>(ff1_w, w1_t, 512);
    wconv_k<<<dim3(16, 16, 48), 256, 0, stream>>>(ff2_w, w2_t, 512);

    for (int l = 0; l < DEPTH; ++l) {
        lngemm_k<1536, 0><<<dim3(12, BATCH), 256, 0, stream>>>(
            t, aln_g + l * DIM, aln_b + l * DIM,
            wq_t + (size_t)l * 1536 * 512, nullptr, qb16, top1,
            DEPTH * DIM, DEPTH * 512 * 1536, 0);
        attn2_k<<<dim3(HEADS, BATCH), 256, 0, stream>>>(qb16, g16);
        mgemm2_k<512, 1><<<dim3(4, BATCH), 256, 0, stream>>>(
            g16, wo_t + (size_t)l * 512 * 512, out_b + l * DIM, t, top1,
            DEPTH * 512 * 512, DEPTH * DIM);
        lngemm_k<512, 2><<<dim3(4, BATCH), 256, 0, stream>>>(
            t, fln_g + l * DIM, fln_b + l * DIM,
            w1_t + (size_t)l * 512 * 512, ff1_b + l * DIM, hb16, top1,
            DEPTH * DIM, DEPTH * 512 * 512, DEPTH * DIM);
        mgemm2_k<512, 1><<<dim3(4, BATCH), 256, 0, stream>>>(
            hb16, w2_t + (size_t)l * 512 * 512, ff2_b + l * DIM, t, top1,
            DEPTH * 512 * 512, DEPTH * DIM);
    }
    final_k<<<BATCH, 64, 0, stream>>>(t, final_g, final_b, head_w, head_b, top1, out);
}

// Round 6
// 1354.903 us; speedup vs baseline: 1.5210x; 1.0587x over previous
//
#include <hip/hip_runtime.h>
#include <math.h>

#define EXPERTS 8
#define DEPTH 6
#define DIM 512
#define HEADS 8
#define NCLS 10
#define BATCH 128
#define PD 48
#define NTOK 65

typedef __attribute__((ext_vector_type(4))) float f32x4;
typedef __attribute__((ext_vector_type(8))) __bf16 bf16x8;
typedef unsigned short u16;

__device__ inline u16 f2bf(float f) {
    union { float f; unsigned u; } v; v.f = f;
    unsigned r = v.u + 0x7FFFu + ((v.u >> 16) & 1u);
    return (u16)(r >> 16);
}
__device__ inline float bf2f(u16 s) {
    union { unsigned u; float f; } v; v.u = ((unsigned)s) << 16;
    return v.f;
}

// ---------------------------------------------------------------------------
// Gate (exact fp32 — routing must not flip)
// ---------------------------------------------------------------------------
__global__ __launch_bounds__(256) void gate_k(const float* __restrict__ x,
                                              const float* __restrict__ gw,
                                              const float* __restrict__ gb,
                                              int* __restrict__ top1) {
    int b = blockIdx.x, tid = threadIdx.x;
    const float* xb = x + (size_t)b * 3072;
    float acc[EXPERTS];
#pragma unroll
    for (int e = 0; e < EXPERTS; ++e) acc[e] = 0.f;
    for (int i = tid; i < 3072; i += 256) {
        float xv = xb[i];
#pragma unroll
        for (int e = 0; e < EXPERTS; ++e)
            acc[e] = fmaf(xv, gw[(size_t)e * 3072 + i], acc[e]);
    }
    __shared__ float red[256];
    __shared__ float logits[EXPERTS];
    for (int e = 0; e < EXPERTS; ++e) {
        red[tid] = acc[e];
        __syncthreads();
        for (int s = 128; s > 0; s >>= 1) {
            if (tid < s) red[tid] += red[tid + s];
            __syncthreads();
        }
        if (tid == 0) logits[e] = red[0] + gb[e];
        __syncthreads();
    }
    if (tid == 0) {
        int best = 0;
        float bv = logits[0];
        for (int e = 1; e < EXPERTS; ++e)
            if (logits[e] > bv) { bv = logits[e]; best = e; }
        top1[b] = best;
    }
}

// ---------------------------------------------------------------------------
// Routing: perm[128] = item indices sorted (stably) by expert.
// ---------------------------------------------------------------------------
__global__ __launch_bounds__(128) void route2_k(const int* __restrict__ top1,
                                                int* __restrict__ perm) {
    __shared__ int t1[BATCH];
    int tid = threadIdx.x;
    t1[tid] = top1[tid];
    __syncthreads();
    if (tid != 0) return;
    int p = 0;
    for (int e = 0; e < EXPERTS; ++e)
        for (int b = 0; b < BATCH; ++b)
            if (t1[b] == e) perm[p++] = b;
}

// ---------------------------------------------------------------------------
// Patch embed (fp32, writes residual stream t)
// ---------------------------------------------------------------------------
__global__ __launch_bounds__(256) void patch_k(const float* __restrict__ x,
                                               const float* __restrict__ pln1_g,
                                               const float* __restrict__ pln1_b,
                                               const float* __restrict__ patch_w,
                                               const float* __restrict__ patch_b,
                                               const float* __restrict__ pln2_g,
                                               const float* __restrict__ pln2_b,
                                               const float* __restrict__ cls_tok,
                                               const float* __restrict__ pos_emb,
                                               const int* __restrict__ top1,
                                               float* __restrict__ t) {
    int n = blockIdx.x, b = blockIdx.y, tid = threadIdx.x;
    int e = top1[b];
    float* trow = t + ((size_t)b * NTOK + n) * DIM;
    const float* pe = pos_emb + ((size_t)e * NTOK + n) * DIM;

    if (n == 0) {
        for (int d = tid; d < DIM; d += 256)
            trow[d] = cls_tok[e * DIM + d] + pe[d];
        return;
    }
    int pi = n - 1, h = pi >> 3, w = pi & 7;
    __shared__ float pv[PD];
    __shared__ float red[256];
    if (tid < PD) {
        int p1 = tid / 12, rem = tid % 12, p2 = rem / 3, c = rem % 3;
        pv[tid] = x[((size_t)b * 3 + c) * 1024 + (h * 4 + p1) * 32 + (w * 4 + p2)];
    }
    __syncthreads();
    float m = 0.f, q = 0.f;
    for (int j = 0; j < PD; ++j) { float v = pv[j]; m += v; q += v * v; }
    m *= (1.f / PD);
    q = q * (1.f / PD) - m * m;
    float rs = rsqrtf(q + 1e-5f);
    __syncthreads();
    if (tid < PD)
        pv[tid] = (pv[tid] - m) * rs * pln1_g[e * PD + tid] + pln1_b[e * PD + tid];
    __syncthreads();

    float acc0 = patch_b[e * DIM + tid];
    float acc1 = patch_b[e * DIM + tid + 256];
    for (int j = 0; j < PD; ++j) {
        float v = pv[j];
        const float* wr = patch_w + ((size_t)e * PD + j) * DIM;
        acc0 = fmaf(v, wr[tid], acc0);
        acc1 = fmaf(v, wr[tid + 256], acc1);
    }
    red[tid] = acc0 + acc1;
    __syncthreads();
    for (int s = 128; s > 0; s >>= 1) {
        if (tid < s) red[tid] += red[tid + s];
        __syncthreads();
    }
    float S = red[0];
    __syncthreads();
    red[tid] = acc0 * acc0 + acc1 * acc1;
    __syncthreads();
    for (int s = 128; s > 0; s >>= 1) {
        if (tid < s) red[tid] += red[tid + s];
        __syncthreads();
    }
    float Q = red[0];
    float mean = S * (1.f / DIM);
    float var = Q * (1.f / DIM) - mean * mean;
    float rs2 = rsqrtf(var + 1e-5f);
    trow[tid]       = (acc0 - mean) * rs2 * pln2_g[e * DIM + tid]       + pln2_b[e * DIM + tid]       + pe[tid];
    trow[tid + 256] = (acc1 - mean) * rs2 * pln2_g[e * DIM + tid + 256] + pln2_b[e * DIM + tid + 256] + pe[tid + 256];
}

// ---------------------------------------------------------------------------
// Weight convert: fp32 [cnt][512][N] -> bf16 [cnt][N][512] (transpose).
// ---------------------------------------------------------------------------
__global__ __launch_bounds__(256) void wconv_k(const float* __restrict__ src,
                                               u16* __restrict__ dst, int N) {
    __shared__ float tile[32][33];
    int n0 = blockIdx.x * 32, k0 = blockIdx.y * 32, m = blockIdx.z;
    const float* s = src + (size_t)m * 512 * N;
    u16* d = dst + (size_t)m * 512 * N;
    int r = threadIdx.x >> 5, c = threadIdx.x & 31;
#pragma unroll
    for (int i = 0; i < 4; ++i)
        tile[r + i * 8][c] = s[(size_t)(k0 + r + i * 8) * N + n0 + c];
    __syncthreads();
#pragma unroll
    for (int i = 0; i < 4; ++i)
        d[(size_t)(n0 + r + i * 8) * 512 + k0 + c] = f2bf(tile[c][r + i * 8]);
}

// ---------------------------------------------------------------------------
// XCD-chunked block decode: grid = 8 * 16 * CT (1-D).
// chunk = XCD (round-robin on physical id), item = perm[chunk*16 + il].
// All blocks of one chunk share <=few experts' weights + 16 items' t in L2.
// ---------------------------------------------------------------------------
__device__ inline void decode_blk(int p, int CT, const int* __restrict__ perm,
                                  int& b, int& ct) {
    int chunk = p & 7;
    int wi = p >> 3;
    int il = wi / CT;
    ct = wi - il * CT;
    b = perm[chunk * 16 + il];
}

// ---------------------------------------------------------------------------
// Fused LayerNorm + MFMA GEMM: C[65,N] = LN(t[b]) @ Wt (bf16, Wt[n][k]).
// 1-D grid 8*16*(N/128), block 256 (4 waves), K-step 64, M=80.
// OP: 0 = store bf16 (qkv); 2 = bias + exact GELU -> bf16 (ff1)
// ---------------------------------------------------------------------------
template <int N, int OP>
__global__ __launch_bounds__(256) void lngemm_k(const float* __restrict__ T,
                                                const float* __restrict__ gbase,
                                                const float* __restrict__ bbase,
                                                const u16* __restrict__ Wtbase,
                                                const float* __restrict__ Bias,
                                                u16* __restrict__ C,
                                                const int* __restrict__ top1,
                                                const int* __restrict__ perm,
                                                int gestride, int westride,
                                                int bestride) {
    int b, ct;
    decode_blk(blockIdx.x, N / 128, perm, b, ct);
    int tid = threadIdx.x;
    int e = top1[b];
    const u16* Wt = Wtbase + (size_t)e * westride;
    const float* gamma = gbase + (size_t)e * gestride;
    const float* beta  = bbase + (size_t)e * gestride;
    int c0 = ct * 128;
    int lane = tid & 63, w = tid >> 6;
    int rl = lane & 15, kg = lane >> 4;

    __shared__ __align__(16) u16 As[80 * 72];
    __shared__ __align__(16) u16 Bs[128 * 72];
    __shared__ float mean_s[65];
    __shared__ float rstd_s[65];

    const float* Tb = T + (size_t)b * NTOK * 512;

    for (int idx = tid; idx < 135; idx += 256) {
        int r = 65 + idx / 9, q = idx % 9;
        *(int4*)&As[r * 72 + q * 8] = (int4){0, 0, 0, 0};
    }
    for (int r = w; r < NTOK; r += 4) {
        float s = 0.f, sq = 0.f;
#pragma unroll
        for (int ii = 0; ii < 8; ++ii) {
            float v = Tb[r * 512 + ii * 64 + lane];
            s += v;
            sq += v * v;
        }
#pragma unroll
        for (int off = 32; off > 0; off >>= 1) {
            s += __shfl_xor(s, off);
            sq += __shfl_xor(sq, off);
        }
        if (lane == 0) {
            float m = s * (1.f / DIM);
            mean_s[r] = m;
            rstd_s[r] = rsqrtf(sq * (1.f / DIM) - m * m + 1e-5f);
        }
    }
    __syncthreads();

    f32x4 acc[5][2];
#pragma unroll
    for (int mt = 0; mt < 5; ++mt)
#pragma unroll
        for (int j = 0; j < 2; ++j) acc[mt][j] = (f32x4){0.f, 0.f, 0.f, 0.f};

    for (int k0 = 0; k0 < 512; k0 += 64) {
        for (int idx = tid; idx < 1040; idx += 256) {
            int r = idx >> 4, q = idx & 15;
            int k = k0 + q * 4;
            float4 v = *(const float4*)&Tb[r * 512 + k];
            float4 g4 = *(const float4*)&gamma[k];
            float4 b4 = *(const float4*)&beta[k];
            float m = mean_s[r], rs = rstd_s[r];
            u16 o4[4];
            o4[0] = f2bf((v.x - m) * rs * g4.x + b4.x);
            o4[1] = f2bf((v.y - m) * rs * g4.y + b4.y);
            o4[2] = f2bf((v.z - m) * rs * g4.z + b4.z);
            o4[3] = f2bf((v.w - m) * rs * g4.w + b4.w);
            *(int2*)&As[r * 72 + q * 4] = *(int2*)o4;
        }
        for (int idx = tid; idx < 1024; idx += 256) {
            int c = idx >> 3, q = idx & 7;
            *(int4*)&Bs[c * 72 + q * 8] = *(const int4*)&Wt[(size_t)(c0 + c) * 512 + k0 + q * 8];
        }
        __syncthreads();
#pragma unroll
        for (int ks = 0; ks < 2; ++ks) {
            bf16x8 bv0 = *(const bf16x8*)&Bs[((w * 2) * 16 + rl) * 72 + ks * 32 + kg * 8];
            bf16x8 bv1 = *(const bf16x8*)&Bs[((w * 2 + 1) * 16 + rl) * 72 + ks * 32 + kg * 8];
#pragma unroll
            for (int mt = 0; mt < 5; ++mt) {
                bf16x8 av = *(const bf16x8*)&As[(mt * 16 + rl) * 72 + ks * 32 + kg * 8];
                acc[mt][0] = __builtin_amdgcn_mfma_f32_16x16x32_bf16(av, bv0, acc[mt][0], 0, 0, 0);
                acc[mt][1] = __builtin_amdgcn_mfma_f32_16x16x32_bf16(av, bv1, acc[mt][1], 0, 0, 0);
            }
        }
        __syncthreads();
    }

    int rh = lane >> 4;
#pragma unroll
    for (int mt = 0; mt < 5; ++mt)
#pragma unroll
        for (int j = 0; j < 2; ++j)
#pragma unroll
            for (int r = 0; r < 4; ++r) {
                int m = mt * 16 + rh * 4 + r;
                if (m >= NTOK) continue;
                int c = c0 + (w * 2 + j) * 16 + rl;
                float v = acc[mt][j][r];
                size_t o = ((size_t)b * NTOK + m) * N + c;
                if (OP == 0) {
                    C[o] = f2bf(v);
                } else {
                    float vb = v + Bias[(size_t)e * bestride + c];
                    float gl = vb * 0.5f * (1.f + erff(vb * 0.70710678118f));
                    C[o] = f2bf(gl);
                }
            }
}

// ---------------------------------------------------------------------------
// MFMA GEMM, bf16 activations in (no LN): C = A @ Wt, OP=1: fp32 += acc+bias.
// 1-D grid 8*16*(N/128), block 256, K-step 64, M=80.
// ---------------------------------------------------------------------------
template <int N, int OP>
__global__ __launch_bounds__(256) void mgemm2_k(const u16* __restrict__ A,
                                                const u16* __restrict__ Wtbase,
                                                const float* __restrict__ Bbase,
                                                void* __restrict__ Cptr,
                                                const int* __restrict__ top1,
                                                const int* __restrict__ perm,
                                                int westride, int bestride) {
    int b, ct;
    decode_blk(blockIdx.x, N / 128, perm, b, ct);
    int tid = threadIdx.x;
    int e = top1[b];
    const u16* Wt = Wtbase + (size_t)e * westride;
    int c0 = ct * 128;
    int lane = tid & 63, w = tid >> 6;
    int rl = lane & 15, kg = lane >> 4;

    __shared__ __align__(16) u16 As[80 * 72];
    __shared__ __align__(16) u16 Bs[128 * 72];

    const u16* Ab = A + (size_t)b * NTOK * 512;

    for (int idx = tid; idx < 135; idx += 256) {
        int r = 65 + idx / 9, q = idx % 9;
        *(int4*)&As[r * 72 + q * 8] = (int4){0, 0, 0, 0};
    }

    f32x4 acc[5][2];
#pragma unroll
    for (int mt = 0; mt < 5; ++mt)
#pragma unroll
        for (int j = 0; j < 2; ++j) acc[mt][j] = (f32x4){0.f, 0.f, 0.f, 0.f};

    for (int k0 = 0; k0 < 512; k0 += 64) {
        for (int idx = tid; idx < 520; idx += 256) {
            int r = idx >> 3, q = idx & 7;
            *(int4*)&As[r * 72 + q * 8] = *(const int4*)&Ab[(size_t)r * 512 + k0 + q * 8];
        }
        for (int idx = tid; idx < 1024; idx += 256) {
            int c = idx >> 3, q = idx & 7;
            *(int4*)&Bs[c * 72 + q * 8] = *(const int4*)&Wt[(size_t)(c0 + c) * 512 + k0 + q * 8];
        }
        __syncthreads();
#pragma unroll
        for (int ks = 0; ks < 2; ++ks) {
            bf16x8 bv0 = *(const bf16x8*)&Bs[((w * 2) * 16 + rl) * 72 + ks * 32 + kg * 8];
            bf16x8 bv1 = *(const bf16x8*)&Bs[((w * 2 + 1) * 16 + rl) * 72 + ks * 32 + kg * 8];
#pragma unroll
            for (int mt = 0; mt < 5; ++mt) {
                bf16x8 av = *(const bf16x8*)&As[(mt * 16 + rl) * 72 + ks * 32 + kg * 8];
                acc[mt][0] = __builtin_amdgcn_mfma_f32_16x16x32_bf16(av, bv0, acc[mt][0], 0, 0, 0);
                acc[mt][1] = __builtin_amdgcn_mfma_f32_16x16x32_bf16(av, bv1, acc[mt][1], 0, 0, 0);
            }
        }
        __syncthreads();
    }

    int rh = lane >> 4;
#pragma unroll
    for (int mt = 0; mt < 5; ++mt)
#pragma unroll
        for (int j = 0; j < 2; ++j)
#pragma unroll
            for (int r = 0; r < 4; ++r) {
                int m = mt * 16 + rh * 4 + r;
                if (m >= NTOK) continue;
                int c = c0 + (w * 2 + j) * 16 + rl;
                float v = acc[mt][j][r];
                size_t o = ((size_t)b * NTOK + m) * N + c;
                if (OP == 0) {
                    ((u16*)Cptr)[o] = f2bf(v);
                } else {
                    float* Cf = (float*)Cptr;
                    Cf[o] += v + Bbase[(size_t)e * bestride + c];
                }
            }
}

// ---------------------------------------------------------------------------
// MFMA attention: block per (b,h), 4 waves. QK^T / softmax-in-reg / PV.
// ---------------------------------------------------------------------------
#define ATT_LDS (23040 / 2 + 8320 / 2 + 12288 / 2)
__global__ __launch_bounds__(256) void attn2_k(const u16* __restrict__ qkv,
                                               u16* __restrict__ o) {
    int h = blockIdx.x, b = blockIdx.y, tid = threadIdx.x;
    __shared__ __align__(16) u16 smem[ATT_LDS];
    u16* Qs = smem;                    // [80][72]
    u16* Ks = smem + 80 * 72;          // [80][72]
    u16* Ps = smem;                    // [80][96]  (aliases Qs+Ks after barrier)
    u16* Vs = smem + 2 * 80 * 72;      // [65][64]
    u16* Vt = Vs + 65 * 64;            // [64][96]

    const u16* base = qkv + (size_t)b * NTOK * 1536 + h * 64;

    for (int idx = tid; idx < 640; idx += 256) {
        int r = idx >> 3, q = idx & 7;
        int4 vq = {0, 0, 0, 0}, vk = {0, 0, 0, 0};
        if (r < NTOK) {
            vq = *(const int4*)&base[(size_t)r * 1536 + q * 8];
            vk = *(const int4*)&base[(size_t)r * 1536 + 512 + q * 8];
        }
        *(int4*)&Qs[r * 72 + q * 8] = vq;
        *(int4*)&Ks[r * 72 + q * 8] = vk;
    }
    for (int idx = tid; idx < 520; idx += 256) {
        int r = idx >> 3, q = idx & 7;
        *(int4*)&Vs[r * 64 + q * 8] = *(const int4*)&base[(size_t)r * 1536 + 1024 + q * 8];
    }
    __syncthreads();

    int lane = tid & 63, w = tid >> 6;
    int rl = lane & 15, kg = lane >> 4, g = lane >> 4;

    f32x4 acc[2][5];
#pragma unroll
    for (int mi = 0; mi < 2; ++mi)
#pragma unroll
        for (int nt = 0; nt < 5; ++nt) acc[mi][nt] = (f32x4){0.f, 0.f, 0.f, 0.f};

#pragma unroll
    for (int mi = 0; mi < 2; ++mi) {
        if (mi == 1 && w != 0) continue;
        int mt = (mi == 0) ? w : 4;
        bf16x8 av0 = *(const bf16x8*)&Qs[(mt * 16 + rl) * 72 + kg * 8];
        bf16x8 av1 = *(const bf16x8*)&Qs[(mt * 16 + rl) * 72 + 32 + kg * 8];
#pragma unroll
        for (int nt = 0; nt < 5; ++nt) {
            bf16x8 bv0 = *(const bf16x8*)&Ks[(nt * 16 + rl) * 72 + kg * 8];
            bf16x8 bv1 = *(const bf16x8*)&Ks[(nt * 16 + rl) * 72 + 32 + kg * 8];
            acc[mi][nt] = __builtin_amdgcn_mfma_f32_16x16x32_bf16(av0, bv0, acc[mi][nt], 0, 0, 0);
            acc[mi][nt] = __builtin_amdgcn_mfma_f32_16x16x32_bf16(av1, bv1, acc[mi][nt], 0, 0, 0);
        }
    }

    for (int idx = tid; idx < 768; idx += 256) {
        int d = idx & 63, kq = idx >> 6;
        u16 tmp[8];
#pragma unroll
        for (int j = 0; j < 8; ++j) {
            int k = kq * 8 + j;
            tmp[j] = (k < NTOK) ? Vs[k * 64 + d] : (u16)0;
        }
        *(int4*)&Vt[d * 96 + kq * 8] = *(int4*)tmp;
    }

#pragma unroll
    for (int mi = 0; mi < 2; ++mi) {
        if (mi == 1 && w != 0) continue;
#pragma unroll
        for (int r = 0; r < 4; ++r) {
            float m = -3.0e38f;
#pragma unroll
            for (int nt = 0; nt < 5; ++nt) {
                float s = acc[mi][nt][r] * 0.125f;
                if (nt * 16 + rl >= NTOK) s = -3.0e38f;
                acc[mi][nt][r] = s;
                m = fmaxf(m, s);
            }
            m = fmaxf(m, __shfl_xor(m, 1));
            m = fmaxf(m, __shfl_xor(m, 2));
            m = fmaxf(m, __shfl_xor(m, 4));
            m = fmaxf(m, __shfl_xor(m, 8));
            float sum = 0.f;
#pragma unroll
            for (int nt = 0; nt < 5; ++nt) {
                float p = expf(acc[mi][nt][r] - m);
                acc[mi][nt][r] = p;
                sum += p;
            }
            sum += __shfl_xor(sum, 1);
            sum += __shfl_xor(sum, 2);
            sum += __shfl_xor(sum, 4);
            sum += __shfl_xor(sum, 8);
            float inv = 1.f / sum;
#pragma unroll
            for (int nt = 0; nt < 5; ++nt) acc[mi][nt][r] *= inv;
        }
    }
    __syncthreads();

#pragma unroll
    for (int mi = 0; mi < 2; ++mi) {
        if (mi == 1 && w != 0) continue;
        int mt = (mi == 0) ? w : 4;
#pragma unroll
        for (int nt = 0; nt < 5; ++nt)
#pragma unroll
            for (int r = 0; r < 4; ++r)
                Ps[(mt * 16 + g * 4 + r) * 96 + nt * 16 + rl] = f2bf(acc[mi][nt][r]);
    }
    for (int idx = tid; idx < 160; idx += 256) {
        int r = idx >> 1, hf = idx & 1;
        *(int4*)&Ps[r * 96 + 80 + hf * 8] = (int4){0, 0, 0, 0};
    }
    __syncthreads();

#pragma unroll
    for (int mi = 0; mi < 2; ++mi) {
        if (mi == 1 && w != 0) continue;
        int mt = (mi == 0) ? w : 4;
#pragma unroll
        for (int dt = 0; dt < 4; ++dt) {
            f32x4 oa = {0.f, 0.f, 0.f, 0.f};
#pragma unroll
            for (int s2 = 0; s2 < 3; ++s2) {
                bf16x8 av = *(const bf16x8*)&Ps[(mt * 16 + rl) * 96 + s2 * 32 + kg * 8];
                bf16x8 bv = *(const bf16x8*)&Vt[(dt * 16 + rl) * 96 + s2 * 32 + kg * 8];
                oa = __builtin_amdgcn_mfma_f32_16x16x32_bf16(av, bv, oa, 0, 0, 0);
            }
#pragma unroll
            for (int r = 0; r < 4; ++r) {
                int row = mt * 16 + g * 4 + r;
                if (row < NTOK)
                    o[((size_t)b * NTOK + row) * DIM + h * 64 + dt * 16 + rl] = f2bf(oa[r]);
            }
        }
    }
}

// ---------------------------------------------------------------------------
// Final LN (row 0) + head (fp32)
// ---------------------------------------------------------------------------
__global__ __launch_bounds__(64) void final_k(const float* __restrict__ t,
                                              const float* __restrict__ fg,
                                              const float* __restrict__ fb,
                                              const float* __restrict__ hw,
                                              const float* __restrict__ hb,
                                              const int* __restrict__ top1,
                                              float* __restrict__ out) {
    int b = blockIdx.x, lane = threadIdx.x;
    int e = top1[b];
    const float* row = t + (size_t)b * NTOK * DIM;
    float v[8], s = 0.f, q = 0.f;
#pragma unroll
    for (int ii = 0; ii < 8; ++ii) {
        v[ii] = row[ii * 64 + lane];
        s += v[ii];
        q += v[ii] * v[ii];
    }
    for (int off = 32; off > 0; off >>= 1) {
        s += __shfl_xor(s, off);
        q += __shfl_xor(q, off);
    }
    float mean = s * (1.f / DIM);
    float var = q * (1.f / DIM) - mean * mean;
    float rs = rsqrtf(var + 1e-5f);
    float nv[8];
#pragma unroll
    for (int ii = 0; ii < 8; ++ii) {
        int d = ii * 64 + lane;
        nv[ii] = (v[ii] - mean) * rs * fg[e * DIM + d] + fb[e * DIM + d];
    }
    for (int c = 0; c < NCLS; ++c) {
        float p = 0.f;
#pragma unroll
        for (int ii = 0; ii < 8; ++ii) {
            int d = ii * 64 + lane;
            p = fmaf(nv[ii], hw[(size_t)e * DIM * NCLS + d * NCLS + c], p);
        }
        for (int off = 32; off > 0; off >>= 1) p += __shfl_xor(p, off);
        if (lane == 0) out[b * NCLS + c] = p + hb[e * NCLS + c];
    }
}

// ---------------------------------------------------------------------------
extern "C" void kernel_launch(void* const* d_in, const int* in_sizes, int n_in,
                              void* d_out, int out_size, void* d_ws, size_t ws_size,
                              hipStream_t stream) {
    const float* x       = (const float*)d_in[0];
    const float* gate_w  = (const float*)d_in[1];
    const float* gate_b  = (const float*)d_in[2];
    const float* pln1_g  = (const float*)d_in[3];
    const float* pln1_b  = (const float*)d_in[4];
    const float* patch_w = (const float*)d_in[5];
    const float* patch_b = (const float*)d_in[6];
    const float* pln2_g  = (const float*)d_in[7];
    const float* pln2_b  = (const float*)d_in[8];
    const float* cls_tok = (const float*)d_in[9];
    const float* pos_emb = (const float*)d_in[10];
    const float* aln_g   = (const float*)d_in[11];
    const float* aln_b   = (const float*)d_in[12];
    const float* qkv_w   = (const float*)d_in[13];
    const float* out_w   = (const float*)d_in[14];
    const float* out_b   = (const float*)d_in[15];
    const float* fln_g   = (const float*)d_in[16];
    const float* fln_b   = (const float*)d_in[17];
    const float* ff1_w   = (const float*)d_in[18];
    const float* ff1_b   = (const float*)d_in[19];
    const float* ff2_w   = (const float*)d_in[20];
    const float* ff2_b   = (const float*)d_in[21];
    const float* final_g = (const float*)d_in[22];
    const float* final_b = (const float*)d_in[23];
    const float* head_w  = (const float*)d_in[24];
    const float* head_b  = (const float*)d_in[25];
    float* out = (float*)d_out;

    // Workspace layout (ws is ~604 MB per harness fill counters; need ~221 MB)
    int* top1 = (int*)d_ws;                                  // 128 ints
    int* perm = top1 + 128;                                  // 128 ints
    float* t  = (float*)((char*)d_ws + 2048);                // fp32 [B,65,512]
    u16* g16  = (u16*)(t + (size_t)BATCH * NTOK * DIM);      // bf16 [B,65,512]  (attn out)
    u16* qb16 = g16 + (size_t)BATCH * NTOK * DIM;            // bf16 [B,65,1536] (qkv out)
    u16* hb16 = qb16 + (size_t)BATCH * NTOK * 1536;          // bf16 [B,65,512]  (ff1 out)
    u16* wq_t = hb16 + (size_t)BATCH * NTOK * DIM;           // bf16 [48][1536][512]
    u16* wo_t = wq_t + (size_t)48 * 1536 * 512;              // bf16 [48][512][512]
    u16* w1_t = wo_t + (size_t)48 * 512 * 512;
    u16* w2_t = w1_t + (size_t)48 * 512 * 512;

    gate_k<<<BATCH, 256, 0, stream>>>(x, gate_w, gate_b, top1);
    route2_k<<<1, 128, 0, stream>>>(top1, perm);
    patch_k<<<dim3(NTOK, BATCH), 256, 0, stream>>>(x, pln1_g, pln1_b, patch_w, patch_b,
                                                   pln2_g, pln2_b, cls_tok, pos_emb, top1, t);
    wconv_k<<<dim3(48, 16, 48), 256, 0, stream>>>(qkv_w, wq_t, 1536);
    wconv_k<<<dim3(16, 16, 48), 256, 0, stream>>>(out_w, wo_t, 512);
    wconv_k<<<dim3(16, 16, 48), 256, 0, stream>>>(ff1_w, w1_t, 512);
    wconv_k<<<dim3(16, 16, 48), 256, 0, stream>>>(ff2_w, w2_t, 512);

    for (int l = 0; l < DEPTH; ++l) {
        lngemm_k<1536, 0><<<8 * 16 * 12, 256, 0, stream>>>(
            t, aln_g + l * DIM, aln_b + l * DIM,
            wq_t + (size_t)l * 1536 * 512, nullptr, qb16, top1, perm,
            DEPTH * DIM, DEPTH * 512 * 1536, 0);
        attn2_k<<<dim3(HEADS, BATCH), 256, 0, stream>>>(qb16, g16);
        mgemm2_k<512, 1><<<8 * 16 * 4, 256, 0, stream>>>(
            g16, wo_t + (size_t)l * 512 * 512, out_b + l * DIM, t, top1, perm,
            DEPTH * 512 * 512, DEPTH * DIM);
        lngemm_k<512, 2><<<8 * 16 * 4, 256, 0, stream>>>(
            t, fln_g + l * DIM, fln_b + l * DIM,
            w1_t + (size_t)l * 512 * 512, ff1_b + l * DIM, hb16, top1, perm,
            DEPTH * DIM, DEPTH * 512 * 512, DEPTH * DIM);
        mgemm2_k<512, 1><<<8 * 16 * 4, 256, 0, stream>>>(
            hb16, w2_t + (size_t)l * 512 * 512, ff2_b + l * DIM, t, top1, perm,
            DEPTH * 512 * 512, DEPTH * DIM);
    }
    final_k<<<BATCH, 64, 0, stream>>>(t, final_g, final_b, head_w, head_b, top1, out);
}